// Round 3
// baseline (196.866 us; speedup 1.0000x reference)
//
#include <hip/hip_runtime.h>
#include <hip/hip_cooperative_groups.h>
#include <math.h>

namespace cg = cooperative_groups;

// Problem constants (from reference)
#define DIM 256
#define NQ  512
#define NK  512

// ws layout (float offsets). ~2.1 MB of the 256 MB ws.
#define WS_A   0                    // A = Q@Wq.T              [NQ][DIM]
#define WS_B   (NQ*DIM)             // B = K@Wk.T + bpost      [NK][DIM]
#define WS_MP  (WS_B + NK*DIM)      // mu_prior                [NK]
#define WS_S   (WS_MP + 512)        // samples                 [NQ][NK]
#define WS_P   (WS_S + NQ*NK)       // KL partials             [256]

// LDS union: one allocation reused across the three phases (~85 KB -> 1 block/CU,
// which is exactly what cooperative residency needs: 256 blocks on 256 CUs).
struct P1 {
    float X[8][DIM];        // staged input rows        8 KB
    float red[2][8][260];   // cross-d-half combine    16.6 KB
};
struct P2 {
    float A[32][260];       // 33.3 KB (stride 260: b128 reads <=2-way alias, free)
    float B[32][260];       // 33.3 KB
    float wm[DIM], wl[DIM]; //  2 KB
    float red[2][256][9];   // 18.4 KB (stride 9: conflict-free)
    float wred[8];
};
struct P3 {
    float w[2][NK];         // softmax numerators   4 KB
    float redbuf[16][DIM];  // context k-split combine 16 KB
    float sred[8], sred2[8], klr[8], sinv[2];
};
union SmemU { P1 p1; P2 p2; P3 p3; };

__global__ __launch_bounds__(512) void fused_kernel(
    const float* __restrict__ Q, const float* __restrict__ Km,
    const float* __restrict__ V, const float* __restrict__ eps,
    const float* __restrict__ W1p, const float* __restrict__ b1p,
    const float* __restrict__ w2p, const float* __restrict__ b2p,
    const float* __restrict__ Wpost, const float* __restrict__ bpost,
    const float* __restrict__ w_mu, const float* __restrict__ b_mu,
    const float* __restrict__ w_lv, const float* __restrict__ b_lv,
    const float* __restrict__ gamma, const float* __restrict__ beta,
    float* __restrict__ out,
    float* __restrict__ Ag, float* __restrict__ Bg, float* __restrict__ MPg,
    float* __restrict__ Sg, float* __restrict__ Pg)
{
    __shared__ SmemU sm;
    cg::grid_group grid = cg::this_grid();
    const int tid = threadIdx.x;
    const int b   = blockIdx.x;

    // ===================== phase 1: A, B, mu_prior =====================
    // blocks 0-63: A (8 Q-rows each) | 64-127: B (8 K-rows) | 128-255: mu_prior (4 K-rows)
    {
        const int job = (b < 64) ? 0 : (b < 128) ? 1 : 2;
        const float* X = (job == 0) ? Q : Km;
        const int r0    = (job < 2) ? ((b & 63) * 8) : ((b - 128) * 4);
        const int nrows = (job < 2) ? 8 : 4;

        for (int i = tid; i < nrows * 64; i += 512) {       // coalesced float4 stage
            int row = i >> 6, c4 = i & 63;
            *(float4*)&sm.p1.X[row][c4 * 4] = *(const float4*)&X[(r0 + row) * DIM + c4 * 4];
        }
        __syncthreads();

        const int c = tid & 255, dh = tid >> 8;             // col, d-half
        const float* W = (job == 2) ? W1p : Wpost;
        const int wstride = (job == 2) ? DIM : 2 * DIM;
        const int wcol    = (job == 1) ? DIM : 0;
        const float* wrow = W + c * wstride + wcol + dh * 128;
        const float* xb = &sm.p1.X[0][dh * 128];

        if (job < 2) {
            float acc[8] = {0.f, 0.f, 0.f, 0.f, 0.f, 0.f, 0.f, 0.f};
            #pragma unroll 8
            for (int d0 = 0; d0 < 128; d0 += 4) {
                float4 w4 = *(const float4*)&wrow[d0];
                #pragma unroll
                for (int r = 0; r < 8; ++r) {
                    float4 x4 = *(const float4*)&xb[r * DIM + d0];   // LDS broadcast
                    acc[r] = fmaf(x4.x, w4.x, acc[r]);
                    acc[r] = fmaf(x4.y, w4.y, acc[r]);
                    acc[r] = fmaf(x4.z, w4.z, acc[r]);
                    acc[r] = fmaf(x4.w, w4.w, acc[r]);
                }
            }
            #pragma unroll
            for (int r = 0; r < 8; ++r) sm.p1.red[dh][r][c] = acc[r];
            __syncthreads();
            if (tid < 256) {
                if (job == 0) {
                    #pragma unroll
                    for (int r = 0; r < 8; ++r)
                        Ag[(r0 + r) * DIM + c] = sm.p1.red[0][r][c] + sm.p1.red[1][r][c];
                } else {
                    float bp = bpost[c];
                    #pragma unroll
                    for (int r = 0; r < 8; ++r)
                        Bg[(r0 + r) * DIM + c] = sm.p1.red[0][r][c] + sm.p1.red[1][r][c] + bp;
                }
            }
        } else {
            float acc[4] = {0.f, 0.f, 0.f, 0.f};
            #pragma unroll 8
            for (int d0 = 0; d0 < 128; d0 += 4) {
                float4 w4 = *(const float4*)&wrow[d0];
                #pragma unroll
                for (int r = 0; r < 4; ++r) {
                    float4 x4 = *(const float4*)&xb[r * DIM + d0];
                    acc[r] = fmaf(x4.x, w4.x, acc[r]);
                    acc[r] = fmaf(x4.y, w4.y, acc[r]);
                    acc[r] = fmaf(x4.z, w4.z, acc[r]);
                    acc[r] = fmaf(x4.w, w4.w, acc[r]);
                }
            }
            #pragma unroll
            for (int r = 0; r < 4; ++r) sm.p1.red[dh][r][c] = acc[r];
            __syncthreads();
            if (tid < 256) {
                float b1 = b1p[c], w2 = w2p[c];
                #pragma unroll
                for (int r = 0; r < 4; ++r)
                    sm.p1.red[0][r][c] =
                        fmaxf(sm.p1.red[0][r][c] + sm.p1.red[1][r][c] + b1, 0.f) * w2;
            }
            __syncthreads();
            const int w = tid >> 6, lane = tid & 63;
            if (w < 4) {
                float v = sm.p1.red[0][w][lane] + sm.p1.red[0][w][lane + 64]
                        + sm.p1.red[0][w][lane + 128] + sm.p1.red[0][w][lane + 192];
                #pragma unroll
                for (int off = 32; off; off >>= 1) v += __shfl_xor(v, off);
                if (lane == 0) MPg[r0 + w] = v + b2p[0] - 0.125f;   // -0.5*sigma_prior^2
            }
        }
    }
    grid.sync();

    // ===================== phase 2: latent -> KL + samples =====================
    // block = one 32x32 (q,k) tile; 2x2 pairs/thread over 256 lanes; d split
    // across thread halves (32-iter inner loop) + LDS combine.
    {
        const int bq0 = (b >> 4) * 32;
        const int bk0 = (b & 15) * 32;

        #pragma unroll
        for (int i = 0; i < 4; ++i) {
            int f4 = tid + 512 * i;            // 0..2047
            int row = f4 >> 6, c4 = f4 & 63;
            *(float4*)&sm.p2.A[row][c4 * 4] = *(const float4*)&Ag[(bq0 + row) * DIM + c4 * 4];
            *(float4*)&sm.p2.B[row][c4 * 4] = *(const float4*)&Bg[(bk0 + row) * DIM + c4 * 4];
        }
        if (tid < 256) { sm.p2.wm[tid] = w_mu[tid]; sm.p2.wl[tid] = w_lv[tid]; }
        __syncthreads();

        const int l  = tid & 255;
        const int dh = tid >> 8;
        const int tq = l >> 4, tk = l & 15;
        const int db = dh * 128;

        float p00 = 0, p01 = 0, p10 = 0, p11 = 0;
        float l00 = 0, l01 = 0, l10 = 0, l11 = 0;

        #pragma unroll 4
        for (int dd = 0; dd < 128; dd += 4) {
            int d0 = db + dd;
            float4 a0 = *(const float4*)&sm.p2.A[tq][d0];
            float4 a1 = *(const float4*)&sm.p2.A[tq + 16][d0];
            float4 b0 = *(const float4*)&sm.p2.B[tk][d0];
            float4 b1 = *(const float4*)&sm.p2.B[tk + 16][d0];
            float4 m4 = *(const float4*)&sm.p2.wm[d0];
            float4 v4 = *(const float4*)&sm.p2.wl[d0];
#define STEP(c) { float r_;                                                      \
            r_ = fmaxf(a0.c + b0.c, 0.f); p00 = fmaf(r_, m4.c, p00); l00 = fmaf(r_, v4.c, l00); \
            r_ = fmaxf(a0.c + b1.c, 0.f); p01 = fmaf(r_, m4.c, p01); l01 = fmaf(r_, v4.c, l01); \
            r_ = fmaxf(a1.c + b0.c, 0.f); p10 = fmaf(r_, m4.c, p10); l10 = fmaf(r_, v4.c, l10); \
            r_ = fmaxf(a1.c + b1.c, 0.f); p11 = fmaf(r_, m4.c, p11); l11 = fmaf(r_, v4.c, l11); }
            STEP(x) STEP(y) STEP(z) STEP(w)
#undef STEP
        }

        sm.p2.red[dh][l][0] = p00; sm.p2.red[dh][l][1] = l00;
        sm.p2.red[dh][l][2] = p01; sm.p2.red[dh][l][3] = l01;
        sm.p2.red[dh][l][4] = p10; sm.p2.red[dh][l][5] = l10;
        sm.p2.red[dh][l][6] = p11; sm.p2.red[dh][l][7] = l11;
        __syncthreads();

        float kls = 0.f;
        if (tid < 256) {
            const float bmu = b_mu[0], blv = b_lv[0];
            const int qa = bq0 + tq, qb = qa + 16;
            const int ka = bk0 + tk, kb = ka + 16;
            const float mpa = MPg[ka], mpb = MPg[kb];
            const float C0 = -0.69314718056f - 0.5f;   // log(sigma_prior) - 0.5

#define FINISH(i, q, k, mp) {                                            \
            float pacc = sm.p2.red[0][tid][2*(i)]   + sm.p2.red[1][tid][2*(i)];   \
            float lacc = sm.p2.red[0][tid][2*(i)+1] + sm.p2.red[1][tid][2*(i)+1]; \
            float lv   = lacc + blv;                                     \
            float phi  = pacc + bmu;                                     \
            float sig  = __expf(0.5f * lv);                              \
            float sig2 = sig * sig;                                      \
            float mu   = phi - 0.5f * sig2;                              \
            float dm   = mu - (mp);                                      \
            kls += C0 - 0.5f * lv + 2.f * (sig2 + dm * dm);              \
            Sg[(q) * NK + (k)] = __expf(mu + sig * eps[(q) * NK + (k)]); }

            FINISH(0, qa, ka, mpa)
            FINISH(1, qa, kb, mpb)
            FINISH(2, qb, ka, mpa)
            FINISH(3, qb, kb, mpb)
#undef FINISH
        }

        #pragma unroll
        for (int off = 32; off; off >>= 1) kls += __shfl_xor(kls, off);
        if ((tid & 63) == 0) sm.p2.wred[tid >> 6] = kls;
        __syncthreads();
        if (tid == 0) {
            float s = 0.f;
            #pragma unroll
            for (int i = 0; i < 8; ++i) s += sm.p2.wred[i];
            Pg[b] = s;
        }
    }
    grid.sync();

    // ===================== phase 3: softmax + context + LN (+ KL finalize) ============
    {
        const int q0 = b * 2;

        if (b == 0) {
            float v = (tid < 256) ? Pg[tid] : 0.f;
            #pragma unroll
            for (int off = 32; off; off >>= 1) v += __shfl_xor(v, off);
            if ((tid & 63) == 0) sm.p3.klr[tid >> 6] = v;
            __syncthreads();
            if (tid == 0) {
                float s = 0.f;
                #pragma unroll
                for (int i = 0; i < 8; ++i) s += sm.p3.klr[i];
                out[NQ * DIM] = s * (1.f / (float)(NQ * NK));
            }
        }

        #pragma unroll
        for (int r = 0; r < 2; ++r) {
            float sv = Sg[(q0 + r) * NK + tid];
            float m = sv;
            #pragma unroll
            for (int off = 32; off; off >>= 1) m = fmaxf(m, __shfl_xor(m, off));
            if ((tid & 63) == 0) sm.p3.sred[tid >> 6] = m;
            __syncthreads();
            m = fmaxf(fmaxf(fmaxf(sm.p3.sred[0], sm.p3.sred[1]), fmaxf(sm.p3.sred[2], sm.p3.sred[3])),
                      fmaxf(fmaxf(sm.p3.sred[4], sm.p3.sred[5]), fmaxf(sm.p3.sred[6], sm.p3.sred[7])));
            float e = __expf(sv - m);
            sm.p3.w[r][tid] = e;
            float sum = e;
            #pragma unroll
            for (int off = 32; off; off >>= 1) sum += __shfl_xor(sum, off);
            __syncthreads();                 // all sred reads done before overwrite
            if ((tid & 63) == 0) sm.p3.sred[tid >> 6] = sum;
            __syncthreads();
            if (tid == 0) {
                float s = 0.f;
                #pragma unroll
                for (int i = 0; i < 8; ++i) s += sm.p3.sred[i];
                sm.p3.sinv[r] = 1.f / s;
            }
            __syncthreads();
        }

        // context: thread -> (colgroup g: 4 cols, ksplit s: 64 k's)
        const int g = tid & 63, s = tid >> 6;
        float a00 = 0, a01 = 0, a02 = 0, a03 = 0;
        float a10 = 0, a11 = 0, a12 = 0, a13 = 0;
        const float* vp = V + s * 64 * DIM + 4 * g;
        #pragma unroll 8
        for (int i = 0; i < 64; ++i) {
            float4 v4 = *(const float4*)(vp + i * DIM);   // 64 lanes x 16B contiguous
            int k = s * 64 + i;
            float w0 = sm.p3.w[0][k], w1 = sm.p3.w[1][k]; // wave-uniform broadcast
            a00 = fmaf(w0, v4.x, a00); a01 = fmaf(w0, v4.y, a01);
            a02 = fmaf(w0, v4.z, a02); a03 = fmaf(w0, v4.w, a03);
            a10 = fmaf(w1, v4.x, a10); a11 = fmaf(w1, v4.y, a11);
            a12 = fmaf(w1, v4.z, a12); a13 = fmaf(w1, v4.w, a13);
        }
        *(float4*)&sm.p3.redbuf[s * 2 + 0][4 * g] = make_float4(a00, a01, a02, a03);
        *(float4*)&sm.p3.redbuf[s * 2 + 1][4 * g] = make_float4(a10, a11, a12, a13);
        __syncthreads();

        const int r = tid >> 8, col = tid & 255;
        float c = 0.f;
        #pragma unroll
        for (int j = 0; j < 8; ++j) c += sm.p3.redbuf[j * 2 + r][col];
        c *= sm.p3.sinv[r];
        float s1v = c, s2v = c * c;
        #pragma unroll
        for (int off = 32; off; off >>= 1) {
            s1v += __shfl_xor(s1v, off);
            s2v += __shfl_xor(s2v, off);
        }
        if ((tid & 63) == 0) { sm.p3.sred[tid >> 6] = s1v; sm.p3.sred2[tid >> 6] = s2v; }
        __syncthreads();
        float mean = (sm.p3.sred[4 * r] + sm.p3.sred[4 * r + 1] + sm.p3.sred[4 * r + 2] + sm.p3.sred[4 * r + 3]) * (1.f / DIM);
        float msq  = (sm.p3.sred2[4 * r] + sm.p3.sred2[4 * r + 1] + sm.p3.sred2[4 * r + 2] + sm.p3.sred2[4 * r + 3]) * (1.f / DIM);
        float var  = msq - mean * mean;
        out[(q0 + r) * DIM + col] = (c - mean) * rsqrtf(var + 1e-5f) * gamma[col] + beta[col];
    }
}

// ---------------------------------------------------------------------------
extern "C" void kernel_launch(void* const* d_in, const int* in_sizes, int n_in,
                              void* d_out, int out_size, void* d_ws, size_t ws_size,
                              hipStream_t stream)
{
    (void)in_sizes; (void)n_in; (void)out_size; (void)ws_size;
    const float* Q     = (const float*)d_in[0];
    const float* Km    = (const float*)d_in[1];
    const float* V     = (const float*)d_in[2];
    const float* eps   = (const float*)d_in[3];
    const float* W1p   = (const float*)d_in[4];
    const float* b1p   = (const float*)d_in[5];
    const float* w2p   = (const float*)d_in[6];
    const float* b2p   = (const float*)d_in[7];
    const float* Wpost = (const float*)d_in[8];
    const float* bpost = (const float*)d_in[9];
    const float* w_mu  = (const float*)d_in[10];
    const float* b_mu  = (const float*)d_in[11];
    const float* w_lv  = (const float*)d_in[12];
    const float* b_lv  = (const float*)d_in[13];
    const float* gamma = (const float*)d_in[14];
    const float* beta  = (const float*)d_in[15];
    float* out = (float*)d_out;
    float* wsf = (float*)d_ws;

    float* Ag  = wsf + WS_A;
    float* Bg  = wsf + WS_B;
    float* MPg = wsf + WS_MP;
    float* Sg  = wsf + WS_S;
    float* Pg  = wsf + WS_P;

    void* args[] = {
        (void*)&Q, (void*)&Km, (void*)&V, (void*)&eps,
        (void*)&W1p, (void*)&b1p, (void*)&w2p, (void*)&b2p,
        (void*)&Wpost, (void*)&bpost, (void*)&w_mu, (void*)&b_mu,
        (void*)&w_lv, (void*)&b_lv, (void*)&gamma, (void*)&beta,
        (void*)&out, (void*)&Ag, (void*)&Bg, (void*)&MPg, (void*)&Sg, (void*)&Pg
    };
    hipLaunchCooperativeKernel((void*)fused_kernel, dim3(256), dim3(512),
                               args, 0, stream);
}

// Round 5
// 122.969 us; speedup vs baseline: 1.6009x; 1.6009x over previous
//
#include <hip/hip_runtime.h>
#include <hip/hip_fp16.h>
#include <math.h>

// Problem constants (from reference)
#define DIM 256
#define NQ  512
#define NK  512

// ws layout (float offsets). ~2.4 MB of the 256 MB ws.
#define WS_A   0                    // A = Q@Wq.T              [NQ][DIM]
#define WS_B   (NQ*DIM)             // B = K@Wk.T + bpost      [NK][DIM]
#define WS_MP  (WS_B + NK*DIM)      // mu_prior                [NK]
#define WS_S   (WS_MP + 512)        // samples                 [NQ][NK]
#define WS_P   (WS_S + NQ*NK)       // KL partials             [256]
#define WS_VH  (WS_P + 256)         // V in fp16               [NK][DIM] halves (256 KB)

// ---------------------------------------------------------------------------
// K1: A = Q@Wq.T ; B = K@Wk.T + bpost ; mu_prior = relu(K@W1p.T+b1p)@w2p+b2p-0.125 ;
//     Vh = fp16(V).
// 400 blocks x 512 threads: jobs 0/1/2 = 128 blocks x 4 rows; job 3 = 16 blocks
// converting V. d-dimension halved across thread halves, LDS combine.
// ---------------------------------------------------------------------------
__global__ __launch_bounds__(512) void k1_precompute(
    const float* __restrict__ Q, const float* __restrict__ Km,
    const float* __restrict__ V,
    const float* __restrict__ W1p, const float* __restrict__ b1p,
    const float* __restrict__ w2p, const float* __restrict__ b2p,
    const float* __restrict__ Wpost, const float* __restrict__ bpost,
    float* __restrict__ A, float* __restrict__ B, float* __restrict__ mu_prior,
    __half2* __restrict__ Vh2)
{
    __shared__ float X_lds[4][DIM];      // 4 KB
    __shared__ float red[2][4][260];     // 8.3 KB
    const int tid = threadIdx.x;
    const int bid = blockIdx.x;
    const int job = bid >> 7;            // 0,1,2 for 0..383; 3 for 384..399

    if (job == 3) {                      // V -> fp16 (65536 float2 pairs total)
        const int pb = (bid - 384) * 4096 + tid;
        #pragma unroll
        for (int j = 0; j < 8; ++j) {
            int p = pb + 512 * j;
            float2 f = ((const float2*)V)[p];
            Vh2[p] = __floats2half2_rn(f.x, f.y);
        }
        return;
    }

    const int r0  = (bid & 127) * 4;
    const float* X = (job == 0) ? Q : Km;
    const float* W = (job == 2) ? W1p : Wpost;
    const int wstride = (job == 2) ? DIM : 2 * DIM;
    const int wcol    = (job == 1) ? DIM : 0;

    if (tid < 256) {                     // stage 4 X rows (coalesced float4)
        int row = tid >> 6, c4 = tid & 63;
        *(float4*)&X_lds[row][c4 * 4] = *(const float4*)&X[(r0 + row) * DIM + c4 * 4];
    }
    __syncthreads();

    const int c  = tid & 255;
    const int dh = tid >> 8;             // 0/1: which 128-wide d-half
    const float* wrow = W + c * wstride + wcol + dh * 128;
    const float* xrow0 = &X_lds[0][dh * 128];

    float acc0 = 0.f, acc1 = 0.f, acc2 = 0.f, acc3 = 0.f;
    #pragma unroll 8
    for (int d0 = 0; d0 < 128; d0 += 4) {
        float4 w4 = *(const float4*)&wrow[d0];
        float4 x0 = *(const float4*)&xrow0[d0];
        float4 x1 = *(const float4*)&xrow0[DIM + d0];
        float4 x2 = *(const float4*)&xrow0[2 * DIM + d0];
        float4 x3 = *(const float4*)&xrow0[3 * DIM + d0];
        acc0 = fmaf(x0.x, w4.x, acc0); acc0 = fmaf(x0.y, w4.y, acc0);
        acc0 = fmaf(x0.z, w4.z, acc0); acc0 = fmaf(x0.w, w4.w, acc0);
        acc1 = fmaf(x1.x, w4.x, acc1); acc1 = fmaf(x1.y, w4.y, acc1);
        acc1 = fmaf(x1.z, w4.z, acc1); acc1 = fmaf(x1.w, w4.w, acc1);
        acc2 = fmaf(x2.x, w4.x, acc2); acc2 = fmaf(x2.y, w4.y, acc2);
        acc2 = fmaf(x2.z, w4.z, acc2); acc2 = fmaf(x2.w, w4.w, acc2);
        acc3 = fmaf(x3.x, w4.x, acc3); acc3 = fmaf(x3.y, w4.y, acc3);
        acc3 = fmaf(x3.z, w4.z, acc3); acc3 = fmaf(x3.w, w4.w, acc3);
    }
    red[dh][0][c] = acc0; red[dh][1][c] = acc1;
    red[dh][2][c] = acc2; red[dh][3][c] = acc3;
    __syncthreads();

    if (job < 2) {
        if (tid < 256) {
            #pragma unroll
            for (int r = 0; r < 4; ++r) {
                float v = red[0][r][c] + red[1][r][c];
                if (job == 0) A[(r0 + r) * DIM + c] = v;
                else          B[(r0 + r) * DIM + c] = v + bpost[c];
            }
        }
    } else {
        if (tid < 256) {
            float b1 = b1p[c], w2 = w2p[c];
            #pragma unroll
            for (int r = 0; r < 4; ++r)
                red[0][r][c] = fmaxf(red[0][r][c] + red[1][r][c] + b1, 0.f) * w2;
        }
        __syncthreads();
        int w = tid >> 6, lane = tid & 63;
        if (w < 4) {
            float v = red[0][w][lane] + red[0][w][lane + 64]
                    + red[0][w][lane + 128] + red[0][w][lane + 192];
            #pragma unroll
            for (int off = 32; off; off >>= 1) v += __shfl_xor(v, off);
            if (lane == 0) mu_prior[r0 + w] = v + b2p[0] - 0.125f;
        }
    }
}

// ---------------------------------------------------------------------------
// K2: per (q,k): latent-dot -> phi/logvar -> KL partial + samples.
// 256 blocks x 512 threads: 32x32 tile, 2x2 pairs/thread over 256 lane-groups,
// d split across thread halves + LDS combine; epilogue spread over all 512.
// ---------------------------------------------------------------------------
__global__ __launch_bounds__(512) void k2_latent(
    const float* __restrict__ A, const float* __restrict__ B,
    const float* __restrict__ mu_prior, const float* __restrict__ eps,
    const float* __restrict__ w_mu, const float* __restrict__ b_mu,
    const float* __restrict__ w_lv, const float* __restrict__ b_lv,
    float* __restrict__ samples, float* __restrict__ partials)
{
    __shared__ float A_lds[32][260];     // 33.3 KB
    __shared__ float B_lds[32][260];     // 33.3 KB
    __shared__ float wm[DIM], wl[DIM];   // 2 KB
    __shared__ float red[2][256][9];     // 18.4 KB, stride 9 -> conflict-free
    __shared__ float wred[8];
    const int tid = threadIdx.x;
    const int bq0 = (blockIdx.x >> 4) * 32;
    const int bk0 = (blockIdx.x & 15) * 32;

    #pragma unroll
    for (int i = 0; i < 4; ++i) {
        int f4 = tid + 512 * i;          // 0..2047
        int row = f4 >> 6, c4 = f4 & 63;
        *(float4*)&A_lds[row][c4 * 4] = *(const float4*)&A[(bq0 + row) * DIM + c4 * 4];
        *(float4*)&B_lds[row][c4 * 4] = *(const float4*)&B[(bk0 + row) * DIM + c4 * 4];
    }
    if (tid < 256) { wm[tid] = w_mu[tid]; wl[tid] = w_lv[tid]; }
    __syncthreads();

    const int l  = tid & 255;
    const int dh = tid >> 8;             // d-half
    const int tq = l >> 4, tk = l & 15;
    const int db = dh * 128;

    float p00 = 0, p01 = 0, p10 = 0, p11 = 0;
    float l00 = 0, l01 = 0, l10 = 0, l11 = 0;

    #pragma unroll 4
    for (int dd = 0; dd < 128; dd += 4) {
        int d0 = db + dd;
        float4 a0 = *(const float4*)&A_lds[tq][d0];
        float4 a1 = *(const float4*)&A_lds[tq + 16][d0];
        float4 b0 = *(const float4*)&B_lds[tk][d0];
        float4 b1 = *(const float4*)&B_lds[tk + 16][d0];
        float4 m4 = *(const float4*)&wm[d0];
        float4 v4 = *(const float4*)&wl[d0];
#define STEP(c) { float r_;                                                      \
        r_ = fmaxf(a0.c + b0.c, 0.f); p00 = fmaf(r_, m4.c, p00); l00 = fmaf(r_, v4.c, l00); \
        r_ = fmaxf(a0.c + b1.c, 0.f); p01 = fmaf(r_, m4.c, p01); l01 = fmaf(r_, v4.c, l01); \
        r_ = fmaxf(a1.c + b0.c, 0.f); p10 = fmaf(r_, m4.c, p10); l10 = fmaf(r_, v4.c, l10); \
        r_ = fmaxf(a1.c + b1.c, 0.f); p11 = fmaf(r_, m4.c, p11); l11 = fmaf(r_, v4.c, l11); }
        STEP(x) STEP(y) STEP(z) STEP(w)
#undef STEP
    }

    red[dh][l][0] = p00; red[dh][l][1] = l00;
    red[dh][l][2] = p01; red[dh][l][3] = l01;
    red[dh][l][4] = p10; red[dh][l][5] = l10;
    red[dh][l][6] = p11; red[dh][l][7] = l11;
    __syncthreads();

    // epilogue: all 512 threads, 2 pairs each (half the serial expf chain)
    float kls = 0.f;
    {
        const float bmu = b_mu[0], blv = b_lv[0];
        const int l2 = tid & 255;
        const int ih = tid >> 8;                  // 0: pairs {0,1} (q=qa); 1: pairs {2,3} (q=qb)
        const int tq2 = l2 >> 4, tk2 = l2 & 15;
        const int q_  = bq0 + tq2 + 16 * ih;
        const int ka_ = bk0 + tk2, kb_ = ka_ + 16;
        const float mpa = mu_prior[ka_], mpb = mu_prior[kb_];
        const float C0 = -0.69314718056f - 0.5f;  // log(sigma_prior) - 0.5

#define FINISH(i, k, mp) {                                          \
        float pacc = red[0][l2][2*(i)]   + red[1][l2][2*(i)];       \
        float lacc = red[0][l2][2*(i)+1] + red[1][l2][2*(i)+1];     \
        float lv   = lacc + blv;                                    \
        float phi  = pacc + bmu;                                    \
        float sig  = __expf(0.5f * lv);                             \
        float sig2 = sig * sig;                                     \
        float mu   = phi - 0.5f * sig2;                             \
        float dm   = mu - (mp);                                     \
        kls += C0 - 0.5f * lv + 2.f * (sig2 + dm * dm);             \
        samples[q_ * NK + (k)] = __expf(mu + sig * eps[q_ * NK + (k)]); }

        FINISH(2 * ih,     ka_, mpa)
        FINISH(2 * ih + 1, kb_, mpb)
#undef FINISH
    }

    #pragma unroll
    for (int off = 32; off; off >>= 1) kls += __shfl_xor(kls, off);
    if ((tid & 63) == 0) wred[tid >> 6] = kls;
    __syncthreads();
    if (tid == 0) {
        float s = 0.f;
        #pragma unroll
        for (int i = 0; i < 8; ++i) s += wred[i];
        partials[blockIdx.x] = s;
    }
}

// ---------------------------------------------------------------------------
// K3: per 2 q-rows: softmax over 512 k (both rows reduced concurrently, 3
// syncs), context = weights@V with fp16 V (half the L2 traffic), fused LN.
// Block 0 additionally finalizes KL. 256 blocks x 512 threads.
// ---------------------------------------------------------------------------
__global__ __launch_bounds__(512) void k3_output(
    const float* __restrict__ samples, const __half2* __restrict__ Vh2,
    const float* __restrict__ gamma, const float* __restrict__ beta,
    const float* __restrict__ partials, float* __restrict__ out)
{
    __shared__ float w_lds[2][NK];       // 4 KB
    __shared__ float redbuf[16][DIM];    // 16 KB
    __shared__ float sred[8][2], ssum[8][2], klr[8], lnred[8][2];
    const int tid = threadIdx.x;
    const int q0 = blockIdx.x * 2;
    const int wv = tid >> 6, lane = tid & 63;

    if (blockIdx.x == 0) {               // KL finalize (partials ready: stream order)
        float v = (tid < 256) ? partials[tid] : 0.f;
        #pragma unroll
        for (int off = 32; off; off >>= 1) v += __shfl_xor(v, off);
        if (lane == 0) klr[wv] = v;
        __syncthreads();
        if (tid == 0) {
            float s = 0.f;
            #pragma unroll
            for (int i = 0; i < 8; ++i) s += klr[i];
            out[NQ * DIM] = s * (1.f / (float)(NQ * NK));
        }
    }

    // ---- softmax (both rows concurrently) ----
    float s0 = samples[q0 * NK + tid];
    float s1 = samples[(q0 + 1) * NK + tid];
    float m0 = s0, m1 = s1;
    #pragma unroll
    for (int off = 32; off; off >>= 1) {
        m0 = fmaxf(m0, __shfl_xor(m0, off));
        m1 = fmaxf(m1, __shfl_xor(m1, off));
    }
    if (lane == 0) { sred[wv][0] = m0; sred[wv][1] = m1; }
    __syncthreads();
    m0 = sred[0][0]; m1 = sred[0][1];
    #pragma unroll
    for (int i = 1; i < 8; ++i) {
        m0 = fmaxf(m0, sred[i][0]);
        m1 = fmaxf(m1, sred[i][1]);
    }
    float e0 = __expf(s0 - m0), e1 = __expf(s1 - m1);
    w_lds[0][tid] = e0;
    w_lds[1][tid] = e1;
    float t0 = e0, t1 = e1;
    #pragma unroll
    for (int off = 32; off; off >>= 1) {
        t0 += __shfl_xor(t0, off);
        t1 += __shfl_xor(t1, off);
    }
    if (lane == 0) { ssum[wv][0] = t0; ssum[wv][1] = t1; }
    __syncthreads();                     // also makes w_lds visible
    float sum0 = 0.f, sum1 = 0.f;
    #pragma unroll
    for (int i = 0; i < 8; ++i) { sum0 += ssum[i][0]; sum1 += ssum[i][1]; }
    const float inv0 = 1.f / sum0, inv1 = 1.f / sum1;

    // ---- context: thread -> (colgroup g: 4 cols, ksplit s: 64 k's), fp16 V ----
    const int g = tid & 63, s = tid >> 6;
    float a00 = 0, a01 = 0, a02 = 0, a03 = 0;
    float a10 = 0, a11 = 0, a12 = 0, a13 = 0;
    const __half2* vp = Vh2 + s * 64 * (DIM / 2) + 2 * g;
    #pragma unroll 8
    for (int i = 0; i < 64; ++i) {
        float2 raw = *(const float2*)(vp + i * (DIM / 2));   // 4 halves, 64x8B contiguous
        __half2 h0 = *(__half2*)&raw.x;
        __half2 h1 = *(__half2*)&raw.y;
        float2 f0 = __half22float2(h0);
        float2 f1 = __half22float2(h1);
        int k = s * 64 + i;
        float w0 = w_lds[0][k], w1 = w_lds[1][k];            // wave-uniform broadcast
        a00 = fmaf(w0, f0.x, a00); a01 = fmaf(w0, f0.y, a01);
        a02 = fmaf(w0, f1.x, a02); a03 = fmaf(w0, f1.y, a03);
        a10 = fmaf(w1, f0.x, a10); a11 = fmaf(w1, f0.y, a11);
        a12 = fmaf(w1, f1.x, a12); a13 = fmaf(w1, f1.y, a13);
    }
    *(float4*)&redbuf[s * 2 + 0][4 * g] = make_float4(a00, a01, a02, a03);
    *(float4*)&redbuf[s * 2 + 1][4 * g] = make_float4(a10, a11, a12, a13);
    __syncthreads();

    // ---- LN: thread -> (row r = tid>>8, col = tid&255) ----
    const int r = tid >> 8, col = tid & 255;
    float c = 0.f;
    #pragma unroll
    for (int j = 0; j < 8; ++j) c += redbuf[j * 2 + r][col];
    c *= (r == 0) ? inv0 : inv1;
    float s1v = c, s2v = c * c;
    #pragma unroll
    for (int off = 32; off; off >>= 1) {
        s1v += __shfl_xor(s1v, off);
        s2v += __shfl_xor(s2v, off);
    }
    if (lane == 0) { lnred[wv][0] = s1v; lnred[wv][1] = s2v; }
    __syncthreads();
    float mean = (lnred[4 * r][0] + lnred[4 * r + 1][0] + lnred[4 * r + 2][0] + lnred[4 * r + 3][0]) * (1.f / DIM);
    float msq  = (lnred[4 * r][1] + lnred[4 * r + 1][1] + lnred[4 * r + 2][1] + lnred[4 * r + 3][1]) * (1.f / DIM);
    float var  = msq - mean * mean;
    out[(q0 + r) * DIM + col] = (c - mean) * rsqrtf(var + 1e-5f) * gamma[col] + beta[col];
}

// ---------------------------------------------------------------------------
extern "C" void kernel_launch(void* const* d_in, const int* in_sizes, int n_in,
                              void* d_out, int out_size, void* d_ws, size_t ws_size,
                              hipStream_t stream)
{
    (void)in_sizes; (void)n_in; (void)out_size; (void)ws_size;
    const float* Q     = (const float*)d_in[0];
    const float* K     = (const float*)d_in[1];
    const float* V     = (const float*)d_in[2];
    const float* eps   = (const float*)d_in[3];
    const float* W1p   = (const float*)d_in[4];
    const float* b1p   = (const float*)d_in[5];
    const float* w2p   = (const float*)d_in[6];
    const float* b2p   = (const float*)d_in[7];
    const float* Wpost = (const float*)d_in[8];
    const float* bpost = (const float*)d_in[9];
    const float* w_mu  = (const float*)d_in[10];
    const float* b_mu  = (const float*)d_in[11];
    const float* w_lv  = (const float*)d_in[12];
    const float* b_lv  = (const float*)d_in[13];
    const float* gamma = (const float*)d_in[14];
    const float* beta  = (const float*)d_in[15];
    float* out = (float*)d_out;
    float* wsf = (float*)d_ws;

    float*   A        = wsf + WS_A;
    float*   B        = wsf + WS_B;
    float*   mu_prior = wsf + WS_MP;
    float*   samples  = wsf + WS_S;
    float*   partials = wsf + WS_P;
    __half2* Vh2      = (__half2*)(wsf + WS_VH);

    k1_precompute<<<dim3(400), dim3(512), 0, stream>>>(
        Q, K, V, W1p, b1p, w2p, b2p, Wpost, bpost, A, B, mu_prior, Vh2);
    k2_latent<<<dim3(256), dim3(512), 0, stream>>>(
        A, B, mu_prior, eps, w_mu, b_mu, w_lv, b_lv, samples, partials);
    k3_output<<<dim3(256), dim3(512), 0, stream>>>(
        samples, Vh2, gamma, beta, partials, out);
}